// Round 7
// baseline (16.514 us; speedup 1.0000x reference)
//
#include <hip/hip_runtime.h>
#include <math.h>

#define NTH 256
#define RPB 256   // rows per block (== NTH)

__device__ __forceinline__ float frcp(float x) { return __builtin_amdgcn_rcpf(x); }

// Clip directed segment A->B against rotated rect (center (ocx,ocy), axis (c,s),
// half-extents heu,hev); return cross(A',B') of clipped sub-segment (0 if empty).
__device__ __forceinline__ float clip_cross(
    float ax, float ay, float bx, float by,
    float ocx, float ocy, float c, float s,
    float heu, float hev)
{
    float dx = bx - ax, dy = by - ay;
    float rx = ax - ocx, ry = ay - ocy;
    float s0u = rx*c + ry*s,  sdu = dx*c + dy*s;
    float s0v = ry*c - rx*s,  sdv = dy*c - dx*s;
    float iu = frcp(sdu), iv = frcp(sdv);
    float ta = (-heu - s0u)*iu, tb = (heu - s0u)*iu;
    float tc = (-hev - s0v)*iv, td = (hev - s0v)*iv;
    float tlu = fminf(ta, tb), thu = fmaxf(ta, tb);
    float tlv = fminf(tc, td), thv = fmaxf(tc, td);
    float tin  = fmaxf(fmaxf(tlu, tlv), 0.0f);
    float tout = fminf(fminf(thu, thv), 1.0f);
    bool ok = tin < tout;
    float Ax = ax + tin*dx,  Ay = ay + tin*dy;
    float Bx = ax + tout*dx, By = ay + tout*dy;
    float cr = Ax*By - Ay*Bx;
    return ok ? cr : 0.0f;
}

__device__ __forceinline__ float iou_loss_one(const float b1[7], const float b2[7], float w)
{
    float zmax = fminf(b1[2]+0.5f*b1[5], b2[2]+0.5f*b2[5]);
    float zmin = fmaxf(b1[2]-0.5f*b1[5], b2[2]-0.5f*b2[5]);
    float dz = fmaxf(zmax - zmin, 0.0f);
    float v1 = b1[3]*b1[4]*b1[5];
    float v2 = b2[3]*b2[4]*b2[5];

    float ox = b2[0] - b1[0], oy = b2[1] - b1[1];
    float ca1 = __cosf(b1[6]), sa1 = __sinf(b1[6]);
    float ca2 = __cosf(b2[6]), sa2 = __sinf(b2[6]);
    float hw1 = 0.5f*b1[3], hl1 = 0.5f*b1[4];
    float hw2 = 0.5f*b2[3], hl2 = 0.5f*b2[4];

    const float dxs[4] = {0.5f,-0.5f,-0.5f,0.5f};
    const float dys[4] = {0.5f,0.5f,-0.5f,-0.5f};
    float px[4], py[4], qx[4], qy[4];
    #pragma unroll
    for (int k = 0; k < 4; ++k) {
        float xs = dxs[k]*b1[3], ys = dys[k]*b1[4];
        px[k] = xs*ca1 - ys*sa1;
        py[k] = xs*sa1 + ys*ca1;
        float xs2 = dxs[k]*b2[3], ys2 = dys[k]*b2[4];
        qx[k] = ox + xs2*ca2 - ys2*sa2;
        qy[k] = oy + xs2*sa2 + ys2*ca2;
    }

    float s2 = 0.0f;
    #pragma unroll
    for (int k = 0; k < 4; ++k) {
        int kn = (k+1)&3;
        s2 += clip_cross(px[k],py[k], px[kn],py[kn], ox,oy, ca2,sa2, hw2,hl2);
        s2 += clip_cross(qx[k],qy[k], qx[kn],qy[kn], 0.0f,0.0f, ca1,sa1, hw1,hl1);
    }
    float area = 0.5f*fabsf(s2);

    float inter_vol = area * dz;
    float iou = inter_vol * frcp(v1 + v2 - inter_vol + 1e-8f);
    return (1.0f - iou) * w;
}

__global__ __launch_bounds__(NTH) void iou_loss_kernel(
    const float* __restrict__ pred, const float* __restrict__ target,
    const float* __restrict__ weight, float* __restrict__ partial, int n)
{
    __shared__ float sp[RPB*7];
    __shared__ float st[RPB*7];
    __shared__ float sw[RPB];

    const int tid = threadIdx.x;
    const int row0 = blockIdx.x * RPB;
    const int nrows = min(RPB, n - row0);
    const int nwords = nrows * 7;
    const int nw4 = nwords >> 2;

    // ---- cooperative staging: linear float4 loads (coalesced, 16B/lane) ----
    const float4* gp = reinterpret_cast<const float4*>(pred + row0*7);
    const float4* gt = reinterpret_cast<const float4*>(target + row0*7);
    float4* lp = reinterpret_cast<float4*>(sp);
    float4* lt = reinterpret_cast<float4*>(st);
    for (int j = tid; j < nw4; j += NTH) { lp[j] = gp[j]; lt[j] = gt[j]; }
    for (int j = (nw4 << 2) + tid; j < nwords; j += NTH) {   // odd tail (rarely taken)
        sp[j] = pred[row0*7 + j]; st[j] = target[row0*7 + j];
    }
    {
        const int nwf4 = nrows >> 2;
        const float4* gw = reinterpret_cast<const float4*>(weight + row0);
        float4* lw = reinterpret_cast<float4*>(sw);
        for (int j = tid; j < nwf4; j += NTH) lw[j] = gw[j];
        for (int j = (nwf4 << 2) + tid; j < nrows; j += NTH) sw[j] = weight[row0 + j];
    }
    __syncthreads();

    // ---- per-thread compute; LDS reads are 2-way bank aliased (free) ----
    float loss = 0.0f;
    if (tid < nrows) {
        float b1[7], b2[7];
        #pragma unroll
        for (int j = 0; j < 7; ++j) { b1[j] = sp[tid*7+j]; b2[j] = st[tid*7+j]; }
        loss = iou_loss_one(b1, b2, sw[tid]);
    }

    // ---- block reduction -> per-block partial (no atomics, no fences) ----
    #pragma unroll
    for (int off = 32; off > 0; off >>= 1) loss += __shfl_down(loss, off, 64);
    __shared__ float wsum[NTH/64];
    int lane = tid & 63, wid = tid >> 6;
    if (lane == 0) wsum[wid] = loss;
    __syncthreads();
    if (tid == 0) {
        float s = 0.0f;
        #pragma unroll
        for (int w = 0; w < NTH/64; ++w) s += wsum[w];
        partial[blockIdx.x] = s;
    }
}

__global__ __launch_bounds__(NTH) void reduce_kernel(
    const float* __restrict__ partial, int nb, float* __restrict__ out, double inv_n)
{
    double s = 0.0;
    for (int j = threadIdx.x; j < nb; j += NTH) s += (double)partial[j];
    #pragma unroll
    for (int off = 32; off > 0; off >>= 1) s += __shfl_down(s, off, 64);
    __shared__ double wsum[NTH/64];
    int lane = threadIdx.x & 63, wid = threadIdx.x >> 6;
    if (lane == 0) wsum[wid] = s;
    __syncthreads();
    if (threadIdx.x == 0) {
        double tot = 0.0;
        #pragma unroll
        for (int w = 0; w < NTH/64; ++w) tot += wsum[w];
        out[0] = (float)(tot * inv_n);
    }
}

extern "C" void kernel_launch(void* const* d_in, const int* in_sizes, int n_in,
                              void* d_out, int out_size, void* d_ws, size_t ws_size,
                              hipStream_t stream) {
    const float* pred   = (const float*)d_in[0];
    const float* target = (const float*)d_in[1];
    const float* weight = (const float*)d_in[2];
    int n = in_sizes[2];
    float* partial = (float*)d_ws;
    int nblocks = (n + RPB - 1) / RPB;
    hipLaunchKernelGGL(iou_loss_kernel, dim3(nblocks), dim3(NTH), 0, stream,
                       pred, target, weight, partial, n);
    hipLaunchKernelGGL(reduce_kernel, dim3(1), dim3(NTH), 0, stream,
                       partial, nblocks, (float*)d_out, 1.0 / (double)n);
}

// Round 8
// 15.772 us; speedup vs baseline: 1.0471x; 1.0471x over previous
//
#include <hip/hip_runtime.h>
#include <math.h>

#define NTH 256

__device__ __forceinline__ float frcp(float x) { return __builtin_amdgcn_rcpf(x); }

// Clip directed segment A->B against rotated rect (center (ocx,ocy), axis (c,s),
// half-extents heu,hev); return cross(A',B') of clipped sub-segment (0 if empty).
__device__ __forceinline__ float clip_cross(
    float ax, float ay, float bx, float by,
    float ocx, float ocy, float c, float s,
    float heu, float hev)
{
    float dx = bx - ax, dy = by - ay;
    float rx = ax - ocx, ry = ay - ocy;
    float s0u = rx*c + ry*s,  sdu = dx*c + dy*s;
    float s0v = ry*c - rx*s,  sdv = dy*c - dx*s;
    float iu = frcp(sdu), iv = frcp(sdv);
    float ta = (-heu - s0u)*iu, tb = (heu - s0u)*iu;
    float tc = (-hev - s0v)*iv, td = (hev - s0v)*iv;
    float tlu = fminf(ta, tb), thu = fmaxf(ta, tb);
    float tlv = fminf(tc, td), thv = fmaxf(tc, td);
    float tin  = fmaxf(fmaxf(tlu, tlv), 0.0f);
    float tout = fminf(fminf(thu, thv), 1.0f);
    bool ok = tin < tout;
    float Ax = ax + tin*dx,  Ay = ay + tin*dy;
    float Bx = ax + tout*dx, By = ay + tout*dy;
    float cr = Ax*By - Ay*Bx;
    return ok ? cr : 0.0f;
}

__device__ __forceinline__ float iou_loss_one(const float b1[7], const float b2[7], float w)
{
    float zmax = fminf(b1[2]+0.5f*b1[5], b2[2]+0.5f*b2[5]);
    float zmin = fmaxf(b1[2]-0.5f*b1[5], b2[2]-0.5f*b2[5]);
    float dz = fmaxf(zmax - zmin, 0.0f);
    float v1 = b1[3]*b1[4]*b1[5];
    float v2 = b2[3]*b2[4]*b2[5];

    float ox = b2[0] - b1[0], oy = b2[1] - b1[1];
    float ca1 = __cosf(b1[6]), sa1 = __sinf(b1[6]);
    float ca2 = __cosf(b2[6]), sa2 = __sinf(b2[6]);
    float hw1 = 0.5f*b1[3], hl1 = 0.5f*b1[4];
    float hw2 = 0.5f*b2[3], hl2 = 0.5f*b2[4];

    const float dxs[4] = {0.5f,-0.5f,-0.5f,0.5f};
    const float dys[4] = {0.5f,0.5f,-0.5f,-0.5f};
    float px[4], py[4], qx[4], qy[4];
    #pragma unroll
    for (int k = 0; k < 4; ++k) {
        float xs = dxs[k]*b1[3], ys = dys[k]*b1[4];
        px[k] = xs*ca1 - ys*sa1;
        py[k] = xs*sa1 + ys*ca1;
        float xs2 = dxs[k]*b2[3], ys2 = dys[k]*b2[4];
        qx[k] = ox + xs2*ca2 - ys2*sa2;
        qy[k] = oy + xs2*sa2 + ys2*ca2;
    }

    float s2 = 0.0f;
    #pragma unroll
    for (int k = 0; k < 4; ++k) {
        int kn = (k+1)&3;
        s2 += clip_cross(px[k],py[k], px[kn],py[kn], ox,oy, ca2,sa2, hw2,hl2);
        s2 += clip_cross(qx[k],qy[k], qx[kn],qy[kn], 0.0f,0.0f, ca1,sa1, hw1,hl1);
    }
    float area = 0.5f*fabsf(s2);

    float inter_vol = area * dz;
    float iou = inter_vol * frcp(v1 + v2 - inter_vol + 1e-8f);
    return (1.0f - iou) * w;
}

// min 1 wave/EU: lift the VGPR cap (default heuristic was 64 VGPR -> spills)
__global__ __launch_bounds__(NTH, 1) void iou_loss_kernel(
    const float* __restrict__ pred, const float* __restrict__ target,
    const float* __restrict__ weight, float* __restrict__ partial, int n)
{
    int i = blockIdx.x * blockDim.x + threadIdx.x;
    float loss = 0.0f;
    if (i < n) {
        float b1[7], b2[7];
        #pragma unroll
        for (int j = 0; j < 7; ++j) { b1[j] = pred[i*7+j]; b2[j] = target[i*7+j]; }
        loss = iou_loss_one(b1, b2, weight[i]);
    }

    // block reduction -> per-block partial (no atomics, no fences)
    #pragma unroll
    for (int off = 32; off > 0; off >>= 1) loss += __shfl_down(loss, off, 64);
    __shared__ float wsum[NTH/64];
    int lane = threadIdx.x & 63, wid = threadIdx.x >> 6;
    if (lane == 0) wsum[wid] = loss;
    __syncthreads();
    if (threadIdx.x == 0) {
        float s = 0.0f;
        #pragma unroll
        for (int w = 0; w < NTH/64; ++w) s += wsum[w];
        partial[blockIdx.x] = s;
    }
}

__global__ __launch_bounds__(NTH) void reduce_kernel(
    const float* __restrict__ partial, int nb, float* __restrict__ out, double inv_n)
{
    double s = 0.0;
    for (int j = threadIdx.x; j < nb; j += NTH) s += (double)partial[j];
    #pragma unroll
    for (int off = 32; off > 0; off >>= 1) s += __shfl_down(s, off, 64);
    __shared__ double wsum[NTH/64];
    int lane = threadIdx.x & 63, wid = threadIdx.x >> 6;
    if (lane == 0) wsum[wid] = s;
    __syncthreads();
    if (threadIdx.x == 0) {
        double tot = 0.0;
        #pragma unroll
        for (int w = 0; w < NTH/64; ++w) tot += wsum[w];
        out[0] = (float)(tot * inv_n);
    }
}

extern "C" void kernel_launch(void* const* d_in, const int* in_sizes, int n_in,
                              void* d_out, int out_size, void* d_ws, size_t ws_size,
                              hipStream_t stream) {
    const float* pred   = (const float*)d_in[0];
    const float* target = (const float*)d_in[1];
    const float* weight = (const float*)d_in[2];
    int n = in_sizes[2];
    float* partial = (float*)d_ws;
    int nblocks = (n + NTH - 1) / NTH;
    hipLaunchKernelGGL(iou_loss_kernel, dim3(nblocks), dim3(NTH), 0, stream,
                       pred, target, weight, partial, n);
    hipLaunchKernelGGL(reduce_kernel, dim3(1), dim3(NTH), 0, stream,
                       partial, nblocks, (float*)d_out, 1.0 / (double)n);
}